// Round 3
// baseline (427.418 us; speedup 1.0000x reference)
//
#include <hip/hip_runtime.h>
#include <math.h>

#define HID 2048
#define NB  2
#define SEQ 2048
#define NT  (NB*SEQ)   // 4096 tokens
#define NH  16
#define HD  128

typedef __attribute__((ext_vector_type(8))) _Float16 f16x8;  // 8 f16 (4 VGPRs)
typedef __attribute__((ext_vector_type(2))) __fp16   h16x2;  // cvt_pkrtz result type
typedef __attribute__((ext_vector_type(4))) float    f32x4;  // 4 fp32 acc

// softmax scale folded with log2(e): scores in log2 domain -> exp2f.
#define QSCALE 0.12751742f   // (1/sqrt(128)) * log2(e)

__device__ __forceinline__ unsigned short f2h(float x) {   // fp32 -> fp16 (RNE)
    union { _Float16 h; unsigned short u; } c;
    c.h = (_Float16)x;
    return c.u;
}

// ---------------------------------------------------------------------------
// Casts: fp32 -> fp16.
// ---------------------------------------------------------------------------
extern "C" __global__ __launch_bounds__(256)
void cast_x(const float* __restrict__ src, unsigned short* __restrict__ dst, int n4)
{
    const int i = blockIdx.x * 256 + threadIdx.x;
    if (i >= n4) return;
    const float4 x = ((const float4*)src)[i];
    ushort4 h;
    h.x = f2h(x.x); h.y = f2h(x.y); h.z = f2h(x.z); h.w = f2h(x.w);
    ((ushort4*)dst)[i] = h;
}

extern "C" __global__ __launch_bounds__(256)
void cast_w4(const float* __restrict__ s0, const float* __restrict__ s1,
             const float* __restrict__ s2, const float* __restrict__ s3,
             unsigned short* __restrict__ d0, unsigned short* __restrict__ d1,
             unsigned short* __restrict__ d2, unsigned short* __restrict__ d3,
             int n4)
{
    const int which = blockIdx.y;
    const float* __restrict__ src =
        (which==0) ? s0 : (which==1) ? s1 : (which==2) ? s2 : s3;
    unsigned short* __restrict__ dst =
        (which==0) ? d0 : (which==1) ? d1 : (which==2) ? d2 : d3;
    const int i = blockIdx.x * 256 + threadIdx.x;
    if (i >= n4) return;
    const float4 x = ((const float4*)src)[i];
    ushort4 h;
    h.x = f2h(x.x); h.y = f2h(x.y); h.z = f2h(x.z); h.w = f2h(x.w);
    ((ushort4*)dst)[i] = h;
}

// ---------------------------------------------------------------------------
// Kernel 1: fused QKV projection — 256x256 tile, 8-phase deep pipeline.
// 8 waves (2M x 4N), per-wave C = 128x64 (8 m-frags x 4 n-frags, 16x16x32).
// LDS 128 KiB: 2 dbuf x {A 2x[128][64], B 2x[128][64]} f16, XOR-swizzled
// 16B chunks (c ^= row&7) applied on the GLOBAL source (gload_lds dest is
// lane-linear).  Per K-tile: 4 phases x {ds_read subtile; stage 1 half-tile
// (2x gload_lds 16B); s_barrier; setprio(1); 16 MFMA; setprio(0); s_barrier}.
// Phase 0 also reads all 8 B-frags (kept in regs; B-slots die after ph0).
// Stage schedule (issue->need lead >= 3 phases):
//   q0: A0(t+1)  q1: A1(t+1)   -> other buffer (t-1's data, dead)
//   q2: B0(t+2)  q3: B1(t+2)   -> CURRENT buffer's B-slots (dead since q0)
// Once-per-tile wait: vmcnt(4) (keeps B(t+2)'s 4 loads in flight across the
// barrier — never drain to 0 in the main loop; t=30 peels to vmcnt(0)).
// Raw s_barrier throughout (syncthreads would drain vmcnt).
// Grid: linear 384, XCD-major remap: xcd = L&7 -> on0 (each XCD reuses one
// 1 MB B-panel 16x from its private L2).
// ---------------------------------------------------------------------------
extern "C" __global__ __launch_bounds__(512, 2)
void qkv_8ph(const unsigned short* __restrict__ Xh,
             const unsigned short* __restrict__ Wqh,
             const unsigned short* __restrict__ Wkh,
             const unsigned short* __restrict__ Wvh,
             const float* __restrict__ bq, const float* __restrict__ bk,
             const float* __restrict__ bv,
             unsigned short* __restrict__ Qb, unsigned short* __restrict__ Kb,
             unsigned short* __restrict__ Vb)
{
    const int L    = blockIdx.x;
    const int on0  = (L & 7) * 256;          // XCD-major: same on0 per XCD
    const int rest = L >> 3;                 // 0..47
    const int tm0  = (rest & 15) * 256;
    const int which = rest >> 4;             // 0..2
    const unsigned short* __restrict__ W = (which==0) ? Wqh : (which==1) ? Wkh : Wvh;
    const float* __restrict__ bias      = (which==0) ? bq  : (which==1) ? bk  : bv;

    // [buf][half][128*64] f16, 16B-chunk XOR swizzle baked into addresses
    __shared__ alignas(16) unsigned short As[2][2][8192];   // 64 KB
    __shared__ alignas(16) unsigned short Bs[2][2][8192];   // 64 KB

    const int tid  = threadIdx.x;
    const int lane = tid & 63;
    const int w    = tid >> 6;      // 0..7
    const int wm   = w >> 2;        // 0..1  (M half)
    const int wn   = w & 3;         // 0..3  (N quarter)
    const int fr   = lane & 15;
    const int quad = lane >> 4;

#define STAGE_A(tt, hh) do {                                                  \
    const int _b = (tt) & 1;                                                  \
    const unsigned short* _s = Xh + (size_t)(tm0 + (hh)*128)*HID + (tt)*64;   \
    _Pragma("unroll")                                                         \
    for (int _ld = 0; _ld < 2; ++_ld) {                                       \
        const int _p = _ld*512 + tid;                                         \
        const int _r = _p >> 3;                                               \
        const int _c = (_p & 7) ^ (_r & 7);                                   \
        __builtin_amdgcn_global_load_lds(                                     \
            (const __attribute__((address_space(1))) void*)(_s + (size_t)_r*HID + _c*8), \
            (__attribute__((address_space(3))) void*)(&As[_b][hh][_p*8]), 16, 0, 0); \
    } } while(0)

#define STAGE_B(tt, hh) do {                                                  \
    const int _b = (tt) & 1;                                                  \
    const unsigned short* _s = W + (size_t)(on0 + (hh)*128)*HID + (tt)*64;    \
    _Pragma("unroll")                                                         \
    for (int _ld = 0; _ld < 2; ++_ld) {                                       \
        const int _p = _ld*512 + tid;                                         \
        const int _r = _p >> 3;                                               \
        const int _c = (_p & 7) ^ (_r & 7);                                   \
        __builtin_amdgcn_global_load_lds(                                     \
            (const __attribute__((address_space(1))) void*)(_s + (size_t)_r*HID + _c*8), \
            (__attribute__((address_space(3))) void*)(&Bs[_b][hh][_p*8]), 16, 0, 0); \
    } } while(0)

    f32x4 acc[8][4];
    #pragma unroll
    for (int i = 0; i < 8; ++i)
        #pragma unroll
        for (int j = 0; j < 4; ++j)
            acc[i][j] = (f32x4){0.f, 0.f, 0.f, 0.f};

    // ---- prologue: steady-state issue history for tile 0 ----
    // order: B(0,0) B(0,1) A(0,0) A(0,1) B(1,0) B(1,1)  (12 loads)
    STAGE_B(0, 0); STAGE_B(0, 1);
    STAGE_A(0, 0); STAGE_A(0, 1);
    STAGE_B(1, 0); STAGE_B(1, 1);
    asm volatile("s_waitcnt vmcnt(4)" ::: "memory");   // tile 0 fully landed
    __builtin_amdgcn_s_barrier();
    __builtin_amdgcn_sched_barrier(0);

    const int rb0 = (wn & 1) * 64;      // B row base within its half

    for (int t = 0; t < HID/64; ++t) {
        const int cur = t & 1;
        const unsigned short* Acur = &As[cur][wm][0];
        const unsigned short* Bcur = &Bs[cur][wn >> 1][0];

        f16x8 bfr[4][2];
        f16x8 afr[2][2];

        // ---------------- phase 0: all B + A(i=0,1) ----------------
        #pragma unroll
        for (int j = 0; j < 4; ++j)
            #pragma unroll
            for (int kk = 0; kk < 2; ++kk) {
                const int rb = rb0 + j*16 + fr;
                bfr[j][kk] = *(const f16x8*)(Bcur + (rb*8 + ((kk*4 + quad) ^ (rb & 7)))*8);
            }
        #pragma unroll
        for (int il = 0; il < 2; ++il)
            #pragma unroll
            for (int kk = 0; kk < 2; ++kk) {
                const int ra = il*16 + fr;
                afr[il][kk] = *(const f16x8*)(Acur + (ra*8 + ((kk*4 + quad) ^ (ra & 7)))*8);
            }
        if (t + 1 < HID/64) STAGE_A(t + 1, 0);
        __builtin_amdgcn_s_barrier();
        __builtin_amdgcn_s_setprio(1);
        #pragma unroll
        for (int il = 0; il < 2; ++il)
            #pragma unroll
            for (int j = 0; j < 4; ++j)
                #pragma unroll
                for (int kk = 0; kk < 2; ++kk)
                    acc[il][j] = __builtin_amdgcn_mfma_f32_16x16x32_f16(
                        afr[il][kk], bfr[j][kk], acc[il][j], 0, 0, 0);
        __builtin_amdgcn_s_setprio(0);
        __builtin_amdgcn_s_barrier();

        // ---------------- phase 1: A(i=2,3) ----------------
        #pragma unroll
        for (int il = 0; il < 2; ++il)
            #pragma unroll
            for (int kk = 0; kk < 2; ++kk) {
                const int ra = (2 + il)*16 + fr;
                afr[il][kk] = *(const f16x8*)(Acur + (ra*8 + ((kk*4 + quad) ^ (ra & 7)))*8);
            }
        if (t + 1 < HID/64) STAGE_A(t + 1, 1);
        __builtin_amdgcn_s_barrier();
        __builtin_amdgcn_s_setprio(1);
        #pragma unroll
        for (int il = 0; il < 2; ++il)
            #pragma unroll
            for (int j = 0; j < 4; ++j)
                #pragma unroll
                for (int kk = 0; kk < 2; ++kk)
                    acc[2 + il][j] = __builtin_amdgcn_mfma_f32_16x16x32_f16(
                        afr[il][kk], bfr[j][kk], acc[2 + il][j], 0, 0, 0);
        __builtin_amdgcn_s_setprio(0);
        __builtin_amdgcn_s_barrier();

        // ---------------- phase 2: A(i=4,5); B0(t+2) into cur (B dead) ----
        #pragma unroll
        for (int il = 0; il < 2; ++il)
            #pragma unroll
            for (int kk = 0; kk < 2; ++kk) {
                const int ra = (4 + il)*16 + fr;
                afr[il][kk] = *(const f16x8*)(Acur + (ra*8 + ((kk*4 + quad) ^ (ra & 7)))*8);
            }
        if (t + 2 < HID/64) STAGE_B(t + 2, 0);
        __builtin_amdgcn_s_barrier();
        __builtin_amdgcn_s_setprio(1);
        #pragma unroll
        for (int il = 0; il < 2; ++il)
            #pragma unroll
            for (int j = 0; j < 4; ++j)
                #pragma unroll
                for (int kk = 0; kk < 2; ++kk)
                    acc[4 + il][j] = __builtin_amdgcn_mfma_f32_16x16x32_f16(
                        afr[il][kk], bfr[j][kk], acc[4 + il][j], 0, 0, 0);
        __builtin_amdgcn_s_setprio(0);
        __builtin_amdgcn_s_barrier();

        // ---------------- phase 3: A(i=6,7); B1(t+2); tile-boundary wait ----
        #pragma unroll
        for (int il = 0; il < 2; ++il)
            #pragma unroll
            for (int kk = 0; kk < 2; ++kk) {
                const int ra = (6 + il)*16 + fr;
                afr[il][kk] = *(const f16x8*)(Acur + (ra*8 + ((kk*4 + quad) ^ (ra & 7)))*8);
            }
        if (t + 2 < HID/64) STAGE_B(t + 2, 1);
        __builtin_amdgcn_s_barrier();
        __builtin_amdgcn_s_setprio(1);
        #pragma unroll
        for (int il = 0; il < 2; ++il)
            #pragma unroll
            for (int j = 0; j < 4; ++j)
                #pragma unroll
                for (int kk = 0; kk < 2; ++kk)
                    acc[6 + il][j] = __builtin_amdgcn_mfma_f32_16x16x32_f16(
                        afr[il][kk], bfr[j][kk], acc[6 + il][j], 0, 0, 0);
        __builtin_amdgcn_s_setprio(0);
        // counted wait: tile t+1 (A issued q0/q1 this tile, B issued last
        // tile) must be landed; B(t+2)'s 4 loads may stay in flight.
        if (t < HID/64 - 2)      asm volatile("s_waitcnt vmcnt(4)" ::: "memory");
        else if (t == HID/64 - 2) asm volatile("s_waitcnt vmcnt(0)" ::: "memory");
        __builtin_amdgcn_s_barrier();
        __builtin_amdgcn_sched_barrier(0);
    }
#undef STAGE_A
#undef STAGE_B

    // ---- epilogue: C layout col=lane&15, row=quad*4+reg ----
    if (which == 2) {
        #pragma unroll
        for (int j = 0; j < 4; ++j) {
            const int o = on0 + wn*64 + j*16 + fr;
            const float bb = bias[o];
            const int h = o >> 7, d = o & (HD-1);
            #pragma unroll
            for (int i = 0; i < 8; ++i)
                #pragma unroll
                for (int rg = 0; rg < 4; ++rg) {
                    const int tr = tm0 + wm*128 + i*16 + quad*4 + rg;
                    const int b = tr >> 11, s = tr & (SEQ-1);
                    const int pos = (s & ~63) | (((s & 15) << 2) | ((s >> 4) & 3));
                    Vb[((size_t)(b*NH + h)*HD + d)*SEQ + pos] = f2h(acc[i][j][rg] + bb);
                }
        }
    } else {
        const float sc = (which == 0) ? QSCALE : 1.0f;
        unsigned short* __restrict__ dstp = (which == 0) ? Qb : Kb;
        #pragma unroll
        for (int j = 0; j < 4; ++j) {
            const int o = on0 + wn*64 + j*16 + fr;
            const float bb = bias[o];
            const int h = o >> 7, d = o & (HD-1);
            #pragma unroll
            for (int i = 0; i < 8; ++i)
                #pragma unroll
                for (int rg = 0; rg < 4; ++rg) {
                    const int tr = tm0 + wm*128 + i*16 + quad*4 + rg;
                    const int b = tr >> 11, s = tr & (SEQ-1);
                    dstp[((size_t)(b*NH + h)*SEQ + s)*HD + d] =
                        f2h((acc[i][j][rg] + bb) * sc);
                }
        }
    }
}

// ---------------------------------------------------------------------------
// Kernel 2: MFMA flash attention (unchanged from R2: 512 thr / 8 waves,
// 16 Q-rows/wave, cvt_pkrtz P-pack, setprio MFMA clusters).
// ---------------------------------------------------------------------------
#define PS_STRIDE 72   // 64 + 8 pad; 72 ushorts = 144 B = 9*16 B

extern "C" __global__ __launch_bounds__(512, 4)
void attn_mfma(const unsigned short* __restrict__ Qg, const unsigned short* __restrict__ Kg,
               const unsigned short* __restrict__ Vtg, unsigned short* __restrict__ Of)
{
    const int L  = blockIdx.x;
    const int q0 = (L >> 5) * 128;
    const int bh = ((L & 7) << 2) | ((L >> 3) & 3);
    const unsigned short* __restrict__ Qp = Qg  + (size_t)bh * SEQ * HD;
    const unsigned short* __restrict__ Kp = Kg  + (size_t)bh * SEQ * HD;
    const unsigned short* __restrict__ Vp = Vtg + (size_t)bh * HD * SEQ;

    __shared__ alignas(16) unsigned short Ks[64*128];          // 16 KB [s][d]
    __shared__ alignas(16) unsigned short Vts[128*64];         // 16 KB [d][s']
    __shared__ alignas(16) unsigned short Ps[8][16*PS_STRIDE]; // 18 KB

    const int tid  = threadIdx.x;
    const int lane = tid & 63;
    const int w    = tid >> 6;       // 0..7
    const int fr   = lane & 15;
    const int quad = lane >> 4;

    f16x8 qf[4];
    #pragma unroll
    for (int c = 0; c < 4; ++c)
        qf[c] = *(const f16x8*)(Qp + (size_t)(q0 + w*16 + fr)*HD + c*32 + quad*8);

    f32x4 accO[8];
    #pragma unroll
    for (int n = 0; n < 8; ++n)
        accO[n] = (f32x4){0.f, 0.f, 0.f, 0.f};
    float lp[4] = {};

    for (int kt = 0; kt < SEQ/64; ++kt) {
        __syncthreads();                       // prior reads of Ks/Vts done
        {
            const unsigned short* Kt = Kp + (size_t)kt*64*HD;
            #pragma unroll
            for (int r = 0; r < 2; ++r) {
                const int p   = (r*8 + w)*64 + lane;   // 0..1023
                const int row = p >> 4;
                const int c   = (p & 15) ^ (row & 15);
                __builtin_amdgcn_global_load_lds(
                    (const __attribute__((address_space(1))) void*)(Kt + (size_t)row*HD + c*8),
                    (__attribute__((address_space(3))) void*)(Ks + (r*8 + w)*512), 16, 0, 0);
            }
            #pragma unroll
            for (int r = 0; r < 2; ++r) {
                const int p   = (r*8 + w)*64 + lane;
                const int row = p >> 3;                // d 0..127
                const int c   = (p & 7) ^ (row & 7);
                __builtin_amdgcn_global_load_lds(
                    (const __attribute__((address_space(1))) void*)(Vp + (size_t)row*SEQ + kt*64 + c*8),
                    (__attribute__((address_space(3))) void*)(Vts + (r*8 + w)*512), 16, 0, 0);
            }
        }
        __syncthreads();                       // staging complete

        // ---- S = Q K^T (log2 domain) ----
        f32x4 accS[4];
        #pragma unroll
        for (int n = 0; n < 4; ++n)
            accS[n] = (f32x4){0.f, 0.f, 0.f, 0.f};
        #pragma unroll
        for (int c = 0; c < 4; ++c) {
            f16x8 bf[4];
            #pragma unroll
            for (int n = 0; n < 4; ++n)
                bf[n] = *(const f16x8*)(Ks + (n*16 + fr)*128 + ((c*4 + quad) ^ fr)*8);
            __builtin_amdgcn_s_setprio(1);
            #pragma unroll
            for (int n = 0; n < 4; ++n)
                accS[n] = __builtin_amdgcn_mfma_f32_16x16x32_f16(
                    qf[c], bf[n], accS[n], 0, 0, 0);
            __builtin_amdgcn_s_setprio(0);
        }

        // ---- P = exp2(S); pack 4 keys/write at sigma-permuted positions ----
        #pragma unroll
        for (int rg = 0; rg < 4; ++rg) {
            float p0 = exp2f(accS[0][rg]);
            float p1 = exp2f(accS[1][rg]);
            float p2 = exp2f(accS[2][rg]);
            float p3 = exp2f(accS[3][rg]);
            lp[rg] += (p0 + p1) + (p2 + p3);
            union { h16x2 h[2]; ushort4 u4; } pk;
            pk.h[0] = __builtin_amdgcn_cvt_pkrtz(p0, p1);
            pk.h[1] = __builtin_amdgcn_cvt_pkrtz(p2, p3);
            *(ushort4*)(&Ps[w][(quad*4 + rg)*PS_STRIDE + fr*4]) = pk.u4;
        }

        // ---- O += P @ V (keys in sigma order on both sides) ----
        #pragma unroll
        for (int cc = 0; cc < 2; ++cc) {
            f16x8 pf = *(const f16x8*)(&Ps[w][fr*PS_STRIDE + cc*32 + quad*8]);
            f16x8 vf[8];
            #pragma unroll
            for (int n = 0; n < 8; ++n)
                vf[n] = *(const f16x8*)(Vts + (n*16 + fr)*64 + ((cc*4 + quad) ^ (fr & 7))*8);
            __builtin_amdgcn_s_setprio(1);
            #pragma unroll
            for (int n = 0; n < 8; ++n)
                accO[n] = __builtin_amdgcn_mfma_f32_16x16x32_f16(
                    pf, vf[n], accO[n], 0, 0, 0);
            __builtin_amdgcn_s_setprio(0);
        }
    }

    // ---- epilogue: reduce l across the 16 lanes sharing each row ----
    float inv[4];
    #pragma unroll
    for (int rg = 0; rg < 4; ++rg) {
        float l = lp[rg];
        l += __shfl_xor(l, 1);
        l += __shfl_xor(l, 2);
        l += __shfl_xor(l, 4);
        l += __shfl_xor(l, 8);
        inv[rg] = 1.0f / l;
    }
    #pragma unroll
    for (int n = 0; n < 8; ++n) {
        const int d = n*16 + fr;
        #pragma unroll
        for (int rg = 0; rg < 4; ++rg) {
            const int s = q0 + w*16 + quad*4 + rg;
            Of[((size_t)bh*SEQ + s)*HD + d] = f2h(accO[n][rg] * inv[rg]);
        }
    }
}

// ---------------------------------------------------------------------------
// Kernel 3: output projection (unchanged 128² m97-structure).
// ---------------------------------------------------------------------------
extern "C" __global__ __launch_bounds__(256)
void oproj_f16(const unsigned short* __restrict__ Af,
               const unsigned short* __restrict__ Woh,
               const float* __restrict__ bo, float* __restrict__ Y)
{
    const int on0 = blockIdx.x * 128;
    const int tm0 = blockIdx.y * 128;

    __shared__ unsigned short Ah[8192], Bh[8192];   // 2 x 16 KB

    const int tid  = threadIdx.x;
    const int lane = tid & 63;
    const int w    = tid >> 6;
    const int wm   = (w & 1) * 64;
    const int wn   = (w >> 1) * 64;
    const int fr   = lane & 15;
    const int quad = lane >> 4;

    f32x4 acc[4][4];
    #pragma unroll
    for (int i = 0; i < 4; ++i)
        #pragma unroll
        for (int j = 0; j < 4; ++j)
            acc[i][j] = (f32x4){0.f, 0.f, 0.f, 0.f};

    for (int kb = 0; kb < HID/64; ++kb) {
        const int hh  = kb >> 1;
        const int dd0 = (kb & 1) * 64;
        __syncthreads();
        const unsigned short* Bsrc = Woh + (size_t)on0*HID + kb*64;
        #pragma unroll
        for (int r = 0; r < 4; ++r) {
            const int p   = (r*4 + w)*64 + lane;
            const int row = p >> 3;
            const int c   = (p & 7) ^ (row & 7);
            const int t = tm0 + row, b = t >> 11, s = t & (SEQ-1);
            __builtin_amdgcn_global_load_lds(
                (const __attribute__((address_space(1))) void*)
                    (Af + ((size_t)(b*NH + hh)*SEQ + s)*HD + dd0 + c*8),
                (__attribute__((address_space(3))) void*)(Ah + (r*4 + w)*512), 16, 0, 0);
            __builtin_amdgcn_global_load_lds(
                (const __attribute__((address_space(1))) void*)(Bsrc + (size_t)row*HID + c*8),
                (__attribute__((address_space(3))) void*)(Bh + (r*4 + w)*512), 16, 0, 0);
        }
        __syncthreads();

        #pragma unroll
        for (int kk = 0; kk < 2; ++kk) {
            f16x8 a[4], b[4];
            #pragma unroll
            for (int i = 0; i < 4; ++i) {
                const int ra = wm + i*16 + fr;
                a[i] = *(const f16x8*)(Ah + (ra*8 + ((kk*4 + quad) ^ (ra & 7)))*8);
                const int rb = wn + i*16 + fr;
                b[i] = *(const f16x8*)(Bh + (rb*8 + ((kk*4 + quad) ^ (rb & 7)))*8);
            }
            #pragma unroll
            for (int i = 0; i < 4; ++i)
                #pragma unroll
                for (int j = 0; j < 4; ++j)
                    acc[i][j] = __builtin_amdgcn_mfma_f32_16x16x32_f16(a[i], b[j], acc[i][j], 0, 0, 0);
        }
    }

    const int col_l = fr;
    #pragma unroll
    for (int j = 0; j < 4; ++j) {
        const int o = on0 + wn + j*16 + col_l;
        const float bb = bo[o];
        #pragma unroll
        for (int i = 0; i < 4; ++i)
            #pragma unroll
            for (int rg = 0; rg < 4; ++rg) {
                const int t = tm0 + wm + i*16 + quad*4 + rg;
                Y[(size_t)t*HID + o] = acc[i][j][rg] + bb;
            }
    }
}

// ---------------------------------------------------------------------------
// Launch.
// ---------------------------------------------------------------------------
extern "C" void kernel_launch(void* const* d_in, const int* in_sizes, int n_in,
                              void* d_out, int out_size, void* d_ws, size_t ws_size,
                              hipStream_t stream)
{
    const float* X  = (const float*)d_in[0];
    const float* wq = (const float*)d_in[1];
    const float* bq = (const float*)d_in[2];
    const float* wk = (const float*)d_in[3];
    const float* bk = (const float*)d_in[4];
    const float* wv = (const float*)d_in[5];
    const float* bv = (const float*)d_in[6];
    const float* wo = (const float*)d_in[7];
    const float* bo = (const float*)d_in[8];
    float* Y = (float*)d_out;

    const size_t F  = (size_t)NT * HID;    // 8,388,608
    const size_t Wn = (size_t)HID * HID;   // 4,194,304

    unsigned short* Qb  = (unsigned short*)d_ws;
    unsigned short* Kb  = Qb  + F;
    unsigned short* Vb  = Kb  + F;     // [B,H,D,S'] permuted
    unsigned short* Of  = Vb  + F;
    unsigned short* Xh  = Of  + F;
    unsigned short* Wqh = Xh  + F;
    unsigned short* Wkh = Wqh + Wn;
    unsigned short* Wvh = Wkh + Wn;
    unsigned short* Woh = Wvh + Wn;

    cast_x<<<(int)(F/4/256), 256, 0, stream>>>(X, Xh, (int)(F/4));
    cast_w4<<<dim3((int)(Wn/4/256), 4), 256, 0, stream>>>(
        wq, wk, wv, wo, Wqh, Wkh, Wvh, Woh, (int)(Wn/4));

    qkv_8ph<<<dim3(384, 1, 1), 512, 0, stream>>>(
        Xh, Wqh, Wkh, Wvh, bq, bk, bv, Qb, Kb, Vb);

    attn_mfma<<<dim3(512, 1, 1), 512, 0, stream>>>(Qb, Kb, Vb, Of);

    oproj_f16<<<dim3(HID/128, NT/128), 256, 0, stream>>>(Of, Woh, bo, Y);
}

// Round 4
// 405.650 us; speedup vs baseline: 1.0537x; 1.0537x over previous
//
#include <hip/hip_runtime.h>
#include <math.h>

#define HID 2048
#define NB  2
#define SEQ 2048
#define NT  (NB*SEQ)   // 4096 tokens
#define NH  16
#define HD  128

typedef __attribute__((ext_vector_type(8))) _Float16 f16x8;  // 8 f16 (4 VGPRs)
typedef __attribute__((ext_vector_type(2))) __fp16   h16x2;  // cvt_pkrtz result type
typedef __attribute__((ext_vector_type(4))) float    f32x4;  // 4 fp32 acc

// softmax scale folded with log2(e): scores in log2 domain -> exp2f.
#define QSCALE 0.12751742f   // (1/sqrt(128)) * log2(e)

__device__ __forceinline__ unsigned short f2h(float x) {   // fp32 -> fp16 (RNE)
    union { _Float16 h; unsigned short u; } c;
    c.h = (_Float16)x;
    return c.u;
}

// ---------------------------------------------------------------------------
// Casts: fp32 -> fp16.
// ---------------------------------------------------------------------------
extern "C" __global__ __launch_bounds__(256)
void cast_x(const float* __restrict__ src, unsigned short* __restrict__ dst, int n4)
{
    const int i = blockIdx.x * 256 + threadIdx.x;
    if (i >= n4) return;
    const float4 x = ((const float4*)src)[i];
    ushort4 h;
    h.x = f2h(x.x); h.y = f2h(x.y); h.z = f2h(x.z); h.w = f2h(x.w);
    ((ushort4*)dst)[i] = h;
}

extern "C" __global__ __launch_bounds__(256)
void cast_w4(const float* __restrict__ s0, const float* __restrict__ s1,
             const float* __restrict__ s2, const float* __restrict__ s3,
             unsigned short* __restrict__ d0, unsigned short* __restrict__ d1,
             unsigned short* __restrict__ d2, unsigned short* __restrict__ d3,
             int n4)
{
    const int which = blockIdx.y;
    const float* __restrict__ src =
        (which==0) ? s0 : (which==1) ? s1 : (which==2) ? s2 : s3;
    unsigned short* __restrict__ dst =
        (which==0) ? d0 : (which==1) ? d1 : (which==2) ? d2 : d3;
    const int i = blockIdx.x * 256 + threadIdx.x;
    if (i >= n4) return;
    const float4 x = ((const float4*)src)[i];
    ushort4 h;
    h.x = f2h(x.x); h.y = f2h(x.y); h.z = f2h(x.z); h.w = f2h(x.w);
    ((ushort4*)dst)[i] = h;
}

// ---------------------------------------------------------------------------
// Kernel 1: fused QKV projection, single-pass fp16 MFMA (proven 141 us).
// BK=64: A/B tiles 128x64 f16 (16 KB each), swizzle c^(row&7) applied on the
// GLOBAL source address (global_load_lds dest is lane-contiguous by HW).
//   Q -> [B,H,S,D] f16 pre-scaled by QSCALE
//   K -> [B,H,S,D] f16
//   V -> [B,H,D,S'] f16, s' sigma-permuted within 64-blocks:
//        pos = (s&~63) | ((s&15)<<2) | ((s>>4)&3)   (matches attn's P packing)
// ---------------------------------------------------------------------------
extern "C" __global__ __launch_bounds__(256)
void qkv_f16(const unsigned short* __restrict__ Xh,
             const unsigned short* __restrict__ Wqh,
             const unsigned short* __restrict__ Wkh,
             const unsigned short* __restrict__ Wvh,
             const float* __restrict__ bq, const float* __restrict__ bk,
             const float* __restrict__ bv,
             unsigned short* __restrict__ Qb, unsigned short* __restrict__ Kb,
             unsigned short* __restrict__ Vb)
{
    const int on0 = blockIdx.x * 128;
    const int tm0 = blockIdx.y * 128;
    const int which = blockIdx.z;
    const unsigned short* __restrict__ W = (which==0) ? Wqh : (which==1) ? Wkh : Wvh;
    const float* __restrict__ bias      = (which==0) ? bq  : (which==1) ? bk  : bv;

    __shared__ unsigned short Ah[8192], Bh[8192];   // 2 x 16 KB

    const int tid  = threadIdx.x;
    const int lane = tid & 63;
    const int w    = tid >> 6;
    const int wm   = (w & 1) * 64;
    const int wn   = (w >> 1) * 64;
    const int fr   = lane & 15;
    const int quad = lane >> 4;

    f32x4 acc[4][4];
    #pragma unroll
    for (int i = 0; i < 4; ++i)
        #pragma unroll
        for (int j = 0; j < 4; ++j)
            acc[i][j] = (f32x4){0.f, 0.f, 0.f, 0.f};

    for (int kb = 0; kb < HID/64; ++kb) {
        __syncthreads();
        const unsigned short* Asrc = Xh + (size_t)tm0*HID + kb*64;
        const unsigned short* Bsrc = W  + (size_t)on0*HID + kb*64;
        #pragma unroll
        for (int r = 0; r < 4; ++r) {
            const int p   = (r*4 + w)*64 + lane;     // chunk 0..1023
            const int row = p >> 3;
            const int c   = (p & 7) ^ (row & 7);
            __builtin_amdgcn_global_load_lds(
                (const __attribute__((address_space(1))) void*)(Asrc + (size_t)row*HID + c*8),
                (__attribute__((address_space(3))) void*)(Ah + (r*4 + w)*512), 16, 0, 0);
            __builtin_amdgcn_global_load_lds(
                (const __attribute__((address_space(1))) void*)(Bsrc + (size_t)row*HID + c*8),
                (__attribute__((address_space(3))) void*)(Bh + (r*4 + w)*512), 16, 0, 0);
        }
        __syncthreads();

        #pragma unroll
        for (int kk = 0; kk < 2; ++kk) {
            f16x8 a[4], b[4];
            #pragma unroll
            for (int i = 0; i < 4; ++i) {
                const int ra = wm + i*16 + fr;
                a[i] = *(const f16x8*)(Ah + (ra*8 + ((kk*4 + quad) ^ (ra & 7)))*8);
                const int rb = wn + i*16 + fr;
                b[i] = *(const f16x8*)(Bh + (rb*8 + ((kk*4 + quad) ^ (rb & 7)))*8);
            }
            #pragma unroll
            for (int i = 0; i < 4; ++i)
                #pragma unroll
                for (int j = 0; j < 4; ++j)
                    acc[i][j] = __builtin_amdgcn_mfma_f32_16x16x32_f16(a[i], b[j], acc[i][j], 0, 0, 0);
        }
    }

    // epilogue: C layout col=lane&15, row=quad*4+reg
    const int col_l = fr;
    if (which == 2) {
        #pragma unroll
        for (int j = 0; j < 4; ++j) {
            const int o = on0 + wn + j*16 + col_l;
            const float bb = bias[o];
            const int h = o >> 7, d = o & (HD-1);
            #pragma unroll
            for (int i = 0; i < 4; ++i)
                #pragma unroll
                for (int rg = 0; rg < 4; ++rg) {
                    const int t = tm0 + wm + i*16 + quad*4 + rg;
                    const int b = t >> 11, s = t & (SEQ-1);
                    const int pos = (s & ~63) | (((s & 15) << 2) | ((s >> 4) & 3));
                    Vb[((size_t)(b*NH + h)*HD + d)*SEQ + pos] = f2h(acc[i][j][rg] + bb);
                }
        }
    } else {
        const float sc = (which == 0) ? QSCALE : 1.0f;
        unsigned short* __restrict__ dstp = (which == 0) ? Qb : Kb;
        #pragma unroll
        for (int j = 0; j < 4; ++j) {
            const int o = on0 + wn + j*16 + col_l;
            const float bb = bias[o];
            const int h = o >> 7, d = o & (HD-1);
            #pragma unroll
            for (int i = 0; i < 4; ++i)
                #pragma unroll
                for (int rg = 0; rg < 4; ++rg) {
                    const int t = tm0 + wm + i*16 + quad*4 + rg;
                    const int b = t >> 11, s = t & (SEQ-1);
                    dstp[((size_t)(b*NH + h)*SEQ + s)*HD + d] =
                        f2h((acc[i][j][rg] + bb) * sc);
                }
        }
    }
}

// ---------------------------------------------------------------------------
// Kernel 2: MFMA flash attention (512 thr / 8 waves, 16 Q-rows/wave,
// cvt_pkrtz P-pack, setprio MFMA clusters).
// v3: output written TOKEN-MAJOR Of[t][HID] (= [B,S,H,D]) so oproj's
// A-operand read is bit-identical to qkv's row-major X read (the [B,H,S,D]
// layout forced oproj into a 256B-stride 16B gather).  Attn-side cost
// unchanged: same per-thread 2B-store scatter, only the base differs.
// ---------------------------------------------------------------------------
#define PS_STRIDE 72   // 64 + 8 pad; 72 ushorts = 144 B = 9*16 B

extern "C" __global__ __launch_bounds__(512, 4)
void attn_mfma(const unsigned short* __restrict__ Qg, const unsigned short* __restrict__ Kg,
               const unsigned short* __restrict__ Vtg, unsigned short* __restrict__ Of)
{
    const int L  = blockIdx.x;
    const int q0 = (L >> 5) * 128;
    const int bh = ((L & 7) << 2) | ((L >> 3) & 3);
    const unsigned short* __restrict__ Qp = Qg  + (size_t)bh * SEQ * HD;
    const unsigned short* __restrict__ Kp = Kg  + (size_t)bh * SEQ * HD;
    const unsigned short* __restrict__ Vp = Vtg + (size_t)bh * HD * SEQ;

    __shared__ alignas(16) unsigned short Ks[64*128];          // 16 KB [s][d]
    __shared__ alignas(16) unsigned short Vts[128*64];         // 16 KB [d][s']
    __shared__ alignas(16) unsigned short Ps[8][16*PS_STRIDE]; // 18 KB

    const int tid  = threadIdx.x;
    const int lane = tid & 63;
    const int w    = tid >> 6;       // 0..7
    const int fr   = lane & 15;
    const int quad = lane >> 4;

    f16x8 qf[4];
    #pragma unroll
    for (int c = 0; c < 4; ++c)
        qf[c] = *(const f16x8*)(Qp + (size_t)(q0 + w*16 + fr)*HD + c*32 + quad*8);

    f32x4 accO[8];
    #pragma unroll
    for (int n = 0; n < 8; ++n)
        accO[n] = (f32x4){0.f, 0.f, 0.f, 0.f};
    float lp[4] = {};

    for (int kt = 0; kt < SEQ/64; ++kt) {
        __syncthreads();                       // prior reads of Ks/Vts done
        {
            const unsigned short* Kt = Kp + (size_t)kt*64*HD;
            #pragma unroll
            for (int r = 0; r < 2; ++r) {
                const int p   = (r*8 + w)*64 + lane;   // 0..1023
                const int row = p >> 4;
                const int c   = (p & 15) ^ (row & 15);
                __builtin_amdgcn_global_load_lds(
                    (const __attribute__((address_space(1))) void*)(Kt + (size_t)row*HD + c*8),
                    (__attribute__((address_space(3))) void*)(Ks + (r*8 + w)*512), 16, 0, 0);
            }
            #pragma unroll
            for (int r = 0; r < 2; ++r) {
                const int p   = (r*8 + w)*64 + lane;
                const int row = p >> 3;                // d 0..127
                const int c   = (p & 7) ^ (row & 7);
                __builtin_amdgcn_global_load_lds(
                    (const __attribute__((address_space(1))) void*)(Vp + (size_t)row*SEQ + kt*64 + c*8),
                    (__attribute__((address_space(3))) void*)(Vts + (r*8 + w)*512), 16, 0, 0);
            }
        }
        __syncthreads();                       // staging complete

        // ---- S = Q K^T (log2 domain) ----
        f32x4 accS[4];
        #pragma unroll
        for (int n = 0; n < 4; ++n)
            accS[n] = (f32x4){0.f, 0.f, 0.f, 0.f};
        #pragma unroll
        for (int c = 0; c < 4; ++c) {
            f16x8 bf[4];
            #pragma unroll
            for (int n = 0; n < 4; ++n)
                bf[n] = *(const f16x8*)(Ks + (n*16 + fr)*128 + ((c*4 + quad) ^ fr)*8);
            __builtin_amdgcn_s_setprio(1);
            #pragma unroll
            for (int n = 0; n < 4; ++n)
                accS[n] = __builtin_amdgcn_mfma_f32_16x16x32_f16(
                    qf[c], bf[n], accS[n], 0, 0, 0);
            __builtin_amdgcn_s_setprio(0);
        }

        // ---- P = exp2(S); pack 4 keys/write at sigma-permuted positions ----
        #pragma unroll
        for (int rg = 0; rg < 4; ++rg) {
            float p0 = exp2f(accS[0][rg]);
            float p1 = exp2f(accS[1][rg]);
            float p2 = exp2f(accS[2][rg]);
            float p3 = exp2f(accS[3][rg]);
            lp[rg] += (p0 + p1) + (p2 + p3);
            union { h16x2 h[2]; ushort4 u4; } pk;
            pk.h[0] = __builtin_amdgcn_cvt_pkrtz(p0, p1);
            pk.h[1] = __builtin_amdgcn_cvt_pkrtz(p2, p3);
            *(ushort4*)(&Ps[w][(quad*4 + rg)*PS_STRIDE + fr*4]) = pk.u4;
        }

        // ---- O += P @ V (keys in sigma order on both sides) ----
        #pragma unroll
        for (int cc = 0; cc < 2; ++cc) {
            f16x8 pf = *(const f16x8*)(&Ps[w][fr*PS_STRIDE + cc*32 + quad*8]);
            f16x8 vf[8];
            #pragma unroll
            for (int n = 0; n < 8; ++n)
                vf[n] = *(const f16x8*)(Vts + (n*16 + fr)*64 + ((cc*4 + quad) ^ (fr & 7))*8);
            __builtin_amdgcn_s_setprio(1);
            #pragma unroll
            for (int n = 0; n < 8; ++n)
                accO[n] = __builtin_amdgcn_mfma_f32_16x16x32_f16(
                    pf, vf[n], accO[n], 0, 0, 0);
            __builtin_amdgcn_s_setprio(0);
        }
    }

    // ---- epilogue: reduce l across the 16 lanes sharing each row ----
    float inv[4];
    #pragma unroll
    for (int rg = 0; rg < 4; ++rg) {
        float l = lp[rg];
        l += __shfl_xor(l, 1);
        l += __shfl_xor(l, 2);
        l += __shfl_xor(l, 4);
        l += __shfl_xor(l, 8);
        inv[rg] = 1.0f / l;
    }
    const int bb_ = bh >> 4;         // batch
    const int hh_ = bh & (NH - 1);   // head
    #pragma unroll
    for (int n = 0; n < 8; ++n) {
        const int d = n*16 + fr;
        #pragma unroll
        for (int rg = 0; rg < 4; ++rg) {
            const int s = q0 + w*16 + quad*4 + rg;
            // token-major: Of[(b*SEQ+s)][h*HD + d]
            Of[((size_t)(bb_*SEQ + s))*HID + hh_*HD + d] = f2h(accO[n][rg] * inv[rg]);
        }
    }
}

// ---------------------------------------------------------------------------
// Kernel 3: output projection.  A is now token-major [t][HID] f16 (written
// so by attn), making this kernel structurally identical to one matrix of
// qkv_f16: contiguous row-major A, BK=64, 128x128 tile.
// ---------------------------------------------------------------------------
extern "C" __global__ __launch_bounds__(256)
void oproj_f16(const unsigned short* __restrict__ Af,
               const unsigned short* __restrict__ Woh,
               const float* __restrict__ bo, float* __restrict__ Y)
{
    const int on0 = blockIdx.x * 128;
    const int tm0 = blockIdx.y * 128;

    __shared__ unsigned short Ah[8192], Bh[8192];   // 2 x 16 KB

    const int tid  = threadIdx.x;
    const int lane = tid & 63;
    const int w    = tid >> 6;
    const int wm   = (w & 1) * 64;
    const int wn   = (w >> 1) * 64;
    const int fr   = lane & 15;
    const int quad = lane >> 4;

    f32x4 acc[4][4];
    #pragma unroll
    for (int i = 0; i < 4; ++i)
        #pragma unroll
        for (int j = 0; j < 4; ++j)
            acc[i][j] = (f32x4){0.f, 0.f, 0.f, 0.f};

    for (int kb = 0; kb < HID/64; ++kb) {
        __syncthreads();
        const unsigned short* Asrc = Af  + (size_t)tm0*HID + kb*64;
        const unsigned short* Bsrc = Woh + (size_t)on0*HID + kb*64;
        #pragma unroll
        for (int r = 0; r < 4; ++r) {
            const int p   = (r*4 + w)*64 + lane;
            const int row = p >> 3;
            const int c   = (p & 7) ^ (row & 7);
            __builtin_amdgcn_global_load_lds(
                (const __attribute__((address_space(1))) void*)(Asrc + (size_t)row*HID + c*8),
                (__attribute__((address_space(3))) void*)(Ah + (r*4 + w)*512), 16, 0, 0);
            __builtin_amdgcn_global_load_lds(
                (const __attribute__((address_space(1))) void*)(Bsrc + (size_t)row*HID + c*8),
                (__attribute__((address_space(3))) void*)(Bh + (r*4 + w)*512), 16, 0, 0);
        }
        __syncthreads();

        #pragma unroll
        for (int kk = 0; kk < 2; ++kk) {
            f16x8 a[4], b[4];
            #pragma unroll
            for (int i = 0; i < 4; ++i) {
                const int ra = wm + i*16 + fr;
                a[i] = *(const f16x8*)(Ah + (ra*8 + ((kk*4 + quad) ^ (ra & 7)))*8);
                const int rb = wn + i*16 + fr;
                b[i] = *(const f16x8*)(Bh + (rb*8 + ((kk*4 + quad) ^ (rb & 7)))*8);
            }
            #pragma unroll
            for (int i = 0; i < 4; ++i)
                #pragma unroll
                for (int j = 0; j < 4; ++j)
                    acc[i][j] = __builtin_amdgcn_mfma_f32_16x16x32_f16(a[i], b[j], acc[i][j], 0, 0, 0);
        }
    }

    const int col_l = fr;
    #pragma unroll
    for (int j = 0; j < 4; ++j) {
        const int o = on0 + wn + j*16 + col_l;
        const float bb = bo[o];
        #pragma unroll
        for (int i = 0; i < 4; ++i)
            #pragma unroll
            for (int rg = 0; rg < 4; ++rg) {
                const int t = tm0 + wm + i*16 + quad*4 + rg;
                Y[(size_t)t*HID + o] = acc[i][j][rg] + bb;
            }
    }
}

// ---------------------------------------------------------------------------
// Launch.  Workspace (ushort units, 117 MB):
//   Qb,Kb f16 [B,H,S,D]; Vb f16 [B,H,D,S'] (sigma-permuted)
//   Of f16 [t][HID] token-major (attn output)
//   Xh f16; Wq/Wk/Wv/Wo f16
// ---------------------------------------------------------------------------
extern "C" void kernel_launch(void* const* d_in, const int* in_sizes, int n_in,
                              void* d_out, int out_size, void* d_ws, size_t ws_size,
                              hipStream_t stream)
{
    const float* X  = (const float*)d_in[0];
    const float* wq = (const float*)d_in[1];
    const float* bq = (const float*)d_in[2];
    const float* wk = (const float*)d_in[3];
    const float* bk = (const float*)d_in[4];
    const float* wv = (const float*)d_in[5];
    const float* bv = (const float*)d_in[6];
    const float* wo = (const float*)d_in[7];
    const float* bo = (const float*)d_in[8];
    float* Y = (float*)d_out;

    const size_t F  = (size_t)NT * HID;    // 8,388,608
    const size_t Wn = (size_t)HID * HID;   // 4,194,304

    unsigned short* Qb  = (unsigned short*)d_ws;
    unsigned short* Kb  = Qb  + F;
    unsigned short* Vb  = Kb  + F;     // [B,H,D,S'] permuted
    unsigned short* Of  = Vb  + F;     // token-major [t][HID]
    unsigned short* Xh  = Of  + F;
    unsigned short* Wqh = Xh  + F;
    unsigned short* Wkh = Wqh + Wn;
    unsigned short* Wvh = Wkh + Wn;
    unsigned short* Woh = Wvh + Wn;

    cast_x<<<(int)(F/4/256), 256, 0, stream>>>(X, Xh, (int)(F/4));
    cast_w4<<<dim3((int)(Wn/4/256), 4), 256, 0, stream>>>(
        wq, wk, wv, wo, Wqh, Wkh, Wvh, Woh, (int)(Wn/4));

    qkv_f16<<<dim3(HID/128, NT/128, 3), 256, 0, stream>>>(
        Xh, Wqh, Wkh, Wvh, bq, bk, bv, Qb, Kb, Vb);

    attn_mfma<<<dim3(512, 1, 1), 512, 0, stream>>>(Qb, Kb, Vb, Of);

    oproj_f16<<<dim3(HID/128, NT/128), 256, 0, stream>>>(Of, Woh, bo, Y);
}

// Round 5
// 402.831 us; speedup vs baseline: 1.0610x; 1.0070x over previous
//
#include <hip/hip_runtime.h>
#include <math.h>

#define HID 2048
#define NB  2
#define SEQ 2048
#define NT  (NB*SEQ)   // 4096 tokens
#define NH  16
#define HD  128

typedef __attribute__((ext_vector_type(8))) _Float16 f16x8;  // 8 f16 (4 VGPRs)
typedef __attribute__((ext_vector_type(2))) __fp16   h16x2;  // cvt_pkrtz result type
typedef __attribute__((ext_vector_type(4))) float    f32x4;  // 4 fp32 acc

// softmax scale folded with log2(e): scores in log2 domain -> exp2f.
#define QSCALE 0.12751742f   // (1/sqrt(128)) * log2(e)

__device__ __forceinline__ unsigned short f2h(float x) {   // fp32 -> fp16 (RNE)
    union { _Float16 h; unsigned short u; } c;
    c.h = (_Float16)x;
    return c.u;
}

// ---------------------------------------------------------------------------
// Casts: fp32 -> fp16.
// ---------------------------------------------------------------------------
extern "C" __global__ __launch_bounds__(256)
void cast_x(const float* __restrict__ src, unsigned short* __restrict__ dst, int n4)
{
    const int i = blockIdx.x * 256 + threadIdx.x;
    if (i >= n4) return;
    const float4 x = ((const float4*)src)[i];
    ushort4 h;
    h.x = f2h(x.x); h.y = f2h(x.y); h.z = f2h(x.z); h.w = f2h(x.w);
    ((ushort4*)dst)[i] = h;
}

extern "C" __global__ __launch_bounds__(256)
void cast_w4(const float* __restrict__ s0, const float* __restrict__ s1,
             const float* __restrict__ s2, const float* __restrict__ s3,
             unsigned short* __restrict__ d0, unsigned short* __restrict__ d1,
             unsigned short* __restrict__ d2, unsigned short* __restrict__ d3,
             int n4)
{
    const int which = blockIdx.y;
    const float* __restrict__ src =
        (which==0) ? s0 : (which==1) ? s1 : (which==2) ? s2 : s3;
    unsigned short* __restrict__ dst =
        (which==0) ? d0 : (which==1) ? d1 : (which==2) ? d2 : d3;
    const int i = blockIdx.x * 256 + threadIdx.x;
    if (i >= n4) return;
    const float4 x = ((const float4*)src)[i];
    ushort4 h;
    h.x = f2h(x.x); h.y = f2h(x.y); h.z = f2h(x.z); h.w = f2h(x.w);
    ((ushort4*)dst)[i] = h;
}

// ---------------------------------------------------------------------------
// Kernel 1: fused QKV projection, single-pass fp16 MFMA (proven 141-146 us).
// BK=64: A/B tiles 128x64 f16 (16 KB each), swizzle c^(row&7) applied on the
// GLOBAL source address (global_load_lds dest is lane-contiguous by HW).
//   Q -> [B,H,S,D] f16 pre-scaled by QSCALE
//   K -> [B,H,S,D] f16
//   V -> [B,H,D,S'] f16, s' sigma-permuted within 64-blocks:
//        pos = (s&~63) | ((s&15)<<2) | ((s>>4)&3)   (matches attn's P packing)
// ---------------------------------------------------------------------------
extern "C" __global__ __launch_bounds__(256)
void qkv_f16(const unsigned short* __restrict__ Xh,
             const unsigned short* __restrict__ Wqh,
             const unsigned short* __restrict__ Wkh,
             const unsigned short* __restrict__ Wvh,
             const float* __restrict__ bq, const float* __restrict__ bk,
             const float* __restrict__ bv,
             unsigned short* __restrict__ Qb, unsigned short* __restrict__ Kb,
             unsigned short* __restrict__ Vb)
{
    const int on0 = blockIdx.x * 128;
    const int tm0 = blockIdx.y * 128;
    const int which = blockIdx.z;
    const unsigned short* __restrict__ W = (which==0) ? Wqh : (which==1) ? Wkh : Wvh;
    const float* __restrict__ bias      = (which==0) ? bq  : (which==1) ? bk  : bv;

    __shared__ unsigned short Ah[8192], Bh[8192];   // 2 x 16 KB

    const int tid  = threadIdx.x;
    const int lane = tid & 63;
    const int w    = tid >> 6;
    const int wm   = (w & 1) * 64;
    const int wn   = (w >> 1) * 64;
    const int fr   = lane & 15;
    const int quad = lane >> 4;

    f32x4 acc[4][4];
    #pragma unroll
    for (int i = 0; i < 4; ++i)
        #pragma unroll
        for (int j = 0; j < 4; ++j)
            acc[i][j] = (f32x4){0.f, 0.f, 0.f, 0.f};

    for (int kb = 0; kb < HID/64; ++kb) {
        __syncthreads();
        const unsigned short* Asrc = Xh + (size_t)tm0*HID + kb*64;
        const unsigned short* Bsrc = W  + (size_t)on0*HID + kb*64;
        #pragma unroll
        for (int r = 0; r < 4; ++r) {
            const int p   = (r*4 + w)*64 + lane;     // chunk 0..1023
            const int row = p >> 3;
            const int c   = (p & 7) ^ (row & 7);
            __builtin_amdgcn_global_load_lds(
                (const __attribute__((address_space(1))) void*)(Asrc + (size_t)row*HID + c*8),
                (__attribute__((address_space(3))) void*)(Ah + (r*4 + w)*512), 16, 0, 0);
            __builtin_amdgcn_global_load_lds(
                (const __attribute__((address_space(1))) void*)(Bsrc + (size_t)row*HID + c*8),
                (__attribute__((address_space(3))) void*)(Bh + (r*4 + w)*512), 16, 0, 0);
        }
        __syncthreads();

        #pragma unroll
        for (int kk = 0; kk < 2; ++kk) {
            f16x8 a[4], b[4];
            #pragma unroll
            for (int i = 0; i < 4; ++i) {
                const int ra = wm + i*16 + fr;
                a[i] = *(const f16x8*)(Ah + (ra*8 + ((kk*4 + quad) ^ (ra & 7)))*8);
                const int rb = wn + i*16 + fr;
                b[i] = *(const f16x8*)(Bh + (rb*8 + ((kk*4 + quad) ^ (rb & 7)))*8);
            }
            #pragma unroll
            for (int i = 0; i < 4; ++i)
                #pragma unroll
                for (int j = 0; j < 4; ++j)
                    acc[i][j] = __builtin_amdgcn_mfma_f32_16x16x32_f16(a[i], b[j], acc[i][j], 0, 0, 0);
        }
    }

    // epilogue: C layout col=lane&15, row=quad*4+reg
    const int col_l = fr;
    if (which == 2) {
        #pragma unroll
        for (int j = 0; j < 4; ++j) {
            const int o = on0 + wn + j*16 + col_l;
            const float bb = bias[o];
            const int h = o >> 7, d = o & (HD-1);
            #pragma unroll
            for (int i = 0; i < 4; ++i)
                #pragma unroll
                for (int rg = 0; rg < 4; ++rg) {
                    const int t = tm0 + wm + i*16 + quad*4 + rg;
                    const int b = t >> 11, s = t & (SEQ-1);
                    const int pos = (s & ~63) | (((s & 15) << 2) | ((s >> 4) & 3));
                    Vb[((size_t)(b*NH + h)*HD + d)*SEQ + pos] = f2h(acc[i][j][rg] + bb);
                }
        }
    } else {
        const float sc = (which == 0) ? QSCALE : 1.0f;
        unsigned short* __restrict__ dstp = (which == 0) ? Qb : Kb;
        #pragma unroll
        for (int j = 0; j < 4; ++j) {
            const int o = on0 + wn + j*16 + col_l;
            const float bb = bias[o];
            const int h = o >> 7, d = o & (HD-1);
            #pragma unroll
            for (int i = 0; i < 4; ++i)
                #pragma unroll
                for (int rg = 0; rg < 4; ++rg) {
                    const int t = tm0 + wm + i*16 + quad*4 + rg;
                    const int b = t >> 11, s = t & (SEQ-1);
                    dstp[((size_t)(b*NH + h)*SEQ + s)*HD + d] =
                        f2h((acc[i][j][rg] + bb) * sc);
                }
        }
    }
}

// ---------------------------------------------------------------------------
// Kernel 2: MFMA flash attention (512 thr / 8 waves, 16 Q-rows/wave,
// cvt_pkrtz P-pack, setprio MFMA clusters).  Output token-major Of[t][HID].
// ---------------------------------------------------------------------------
#define PS_STRIDE 72   // 64 + 8 pad; 72 ushorts = 144 B = 9*16 B

extern "C" __global__ __launch_bounds__(512, 4)
void attn_mfma(const unsigned short* __restrict__ Qg, const unsigned short* __restrict__ Kg,
               const unsigned short* __restrict__ Vtg, unsigned short* __restrict__ Of)
{
    const int L  = blockIdx.x;
    const int q0 = (L >> 5) * 128;
    const int bh = ((L & 7) << 2) | ((L >> 3) & 3);
    const unsigned short* __restrict__ Qp = Qg  + (size_t)bh * SEQ * HD;
    const unsigned short* __restrict__ Kp = Kg  + (size_t)bh * SEQ * HD;
    const unsigned short* __restrict__ Vp = Vtg + (size_t)bh * HD * SEQ;

    __shared__ alignas(16) unsigned short Ks[64*128];          // 16 KB [s][d]
    __shared__ alignas(16) unsigned short Vts[128*64];         // 16 KB [d][s']
    __shared__ alignas(16) unsigned short Ps[8][16*PS_STRIDE]; // 18 KB

    const int tid  = threadIdx.x;
    const int lane = tid & 63;
    const int w    = tid >> 6;       // 0..7
    const int fr   = lane & 15;
    const int quad = lane >> 4;

    f16x8 qf[4];
    #pragma unroll
    for (int c = 0; c < 4; ++c)
        qf[c] = *(const f16x8*)(Qp + (size_t)(q0 + w*16 + fr)*HD + c*32 + quad*8);

    f32x4 accO[8];
    #pragma unroll
    for (int n = 0; n < 8; ++n)
        accO[n] = (f32x4){0.f, 0.f, 0.f, 0.f};
    float lp[4] = {};

    for (int kt = 0; kt < SEQ/64; ++kt) {
        __syncthreads();                       // prior reads of Ks/Vts done
        {
            const unsigned short* Kt = Kp + (size_t)kt*64*HD;
            #pragma unroll
            for (int r = 0; r < 2; ++r) {
                const int p   = (r*8 + w)*64 + lane;   // 0..1023
                const int row = p >> 4;
                const int c   = (p & 15) ^ (row & 15);
                __builtin_amdgcn_global_load_lds(
                    (const __attribute__((address_space(1))) void*)(Kt + (size_t)row*HD + c*8),
                    (__attribute__((address_space(3))) void*)(Ks + (r*8 + w)*512), 16, 0, 0);
            }
            #pragma unroll
            for (int r = 0; r < 2; ++r) {
                const int p   = (r*8 + w)*64 + lane;
                const int row = p >> 3;                // d 0..127
                const int c   = (p & 7) ^ (row & 7);
                __builtin_amdgcn_global_load_lds(
                    (const __attribute__((address_space(1))) void*)(Vp + (size_t)row*SEQ + kt*64 + c*8),
                    (__attribute__((address_space(3))) void*)(Vts + (r*8 + w)*512), 16, 0, 0);
            }
        }
        __syncthreads();                       // staging complete

        // ---- S = Q K^T (log2 domain) ----
        f32x4 accS[4];
        #pragma unroll
        for (int n = 0; n < 4; ++n)
            accS[n] = (f32x4){0.f, 0.f, 0.f, 0.f};
        #pragma unroll
        for (int c = 0; c < 4; ++c) {
            f16x8 bf[4];
            #pragma unroll
            for (int n = 0; n < 4; ++n)
                bf[n] = *(const f16x8*)(Ks + (n*16 + fr)*128 + ((c*4 + quad) ^ fr)*8);
            __builtin_amdgcn_s_setprio(1);
            #pragma unroll
            for (int n = 0; n < 4; ++n)
                accS[n] = __builtin_amdgcn_mfma_f32_16x16x32_f16(
                    qf[c], bf[n], accS[n], 0, 0, 0);
            __builtin_amdgcn_s_setprio(0);
        }

        // ---- P = exp2(S); pack 4 keys/write at sigma-permuted positions ----
        #pragma unroll
        for (int rg = 0; rg < 4; ++rg) {
            float p0 = exp2f(accS[0][rg]);
            float p1 = exp2f(accS[1][rg]);
            float p2 = exp2f(accS[2][rg]);
            float p3 = exp2f(accS[3][rg]);
            lp[rg] += (p0 + p1) + (p2 + p3);
            union { h16x2 h[2]; ushort4 u4; } pk;
            pk.h[0] = __builtin_amdgcn_cvt_pkrtz(p0, p1);
            pk.h[1] = __builtin_amdgcn_cvt_pkrtz(p2, p3);
            *(ushort4*)(&Ps[w][(quad*4 + rg)*PS_STRIDE + fr*4]) = pk.u4;
        }

        // ---- O += P @ V (keys in sigma order on both sides) ----
        #pragma unroll
        for (int cc = 0; cc < 2; ++cc) {
            f16x8 pf = *(const f16x8*)(&Ps[w][fr*PS_STRIDE + cc*32 + quad*8]);
            f16x8 vf[8];
            #pragma unroll
            for (int n = 0; n < 8; ++n)
                vf[n] = *(const f16x8*)(Vts + (n*16 + fr)*64 + ((cc*4 + quad) ^ (fr & 7))*8);
            __builtin_amdgcn_s_setprio(1);
            #pragma unroll
            for (int n = 0; n < 8; ++n)
                accO[n] = __builtin_amdgcn_mfma_f32_16x16x32_f16(
                    pf, vf[n], accO[n], 0, 0, 0);
            __builtin_amdgcn_s_setprio(0);
        }
    }

    // ---- epilogue: reduce l across the 16 lanes sharing each row ----
    float inv[4];
    #pragma unroll
    for (int rg = 0; rg < 4; ++rg) {
        float l = lp[rg];
        l += __shfl_xor(l, 1);
        l += __shfl_xor(l, 2);
        l += __shfl_xor(l, 4);
        l += __shfl_xor(l, 8);
        inv[rg] = 1.0f / l;
    }
    const int bb_ = bh >> 4;         // batch
    const int hh_ = bh & (NH - 1);   // head
    #pragma unroll
    for (int n = 0; n < 8; ++n) {
        const int d = n*16 + fr;
        #pragma unroll
        for (int rg = 0; rg < 4; ++rg) {
            const int s = q0 + w*16 + quad*4 + rg;
            // token-major: Of[(b*SEQ+s)][h*HD + d]
            Of[((size_t)(bb_*SEQ + s))*HID + hh_*HD + d] = f2h(accO[n][rg] * inv[rg]);
        }
    }
}

// ---------------------------------------------------------------------------
// Kernel 3: output projection.  v4: 512 threads / 8 waves per 128x128 tile
// (each wave owns 64x32, acc[4][2]) — the 512-block grid was TLP-starved at
// 4 waves (8 waves/CU); this doubles waves/CU to 16 with identical tiles,
// LDS layout and MFMA count.  A is token-major [t][HID] f16 (same read path
// as qkv's X).
// ---------------------------------------------------------------------------
extern "C" __global__ __launch_bounds__(512)
void oproj_f16(const unsigned short* __restrict__ Af,
               const unsigned short* __restrict__ Woh,
               const float* __restrict__ bo, float* __restrict__ Y)
{
    const int on0 = blockIdx.x * 128;
    const int tm0 = blockIdx.y * 128;

    __shared__ unsigned short Ah[8192], Bh[8192];   // 2 x 16 KB

    const int tid  = threadIdx.x;
    const int lane = tid & 63;
    const int w    = tid >> 6;      // 0..7
    const int wm   = (w >> 2) * 64; // 0,64
    const int wn   = (w & 3) * 32;  // 0,32,64,96
    const int fr   = lane & 15;
    const int quad = lane >> 4;

    f32x4 acc[4][2];
    #pragma unroll
    for (int i = 0; i < 4; ++i)
        #pragma unroll
        for (int j = 0; j < 2; ++j)
            acc[i][j] = (f32x4){0.f, 0.f, 0.f, 0.f};

    for (int kb = 0; kb < HID/64; ++kb) {
        __syncthreads();
        const unsigned short* Asrc = Af  + (size_t)tm0*HID + kb*64;
        const unsigned short* Bsrc = Woh + (size_t)on0*HID + kb*64;
        #pragma unroll
        for (int r = 0; r < 2; ++r) {
            const int p   = r*512 + tid;    // chunk 0..1023
            const int row = p >> 3;
            const int c   = (p & 7) ^ (row & 7);
            __builtin_amdgcn_global_load_lds(
                (const __attribute__((address_space(1))) void*)(Asrc + (size_t)row*HID + c*8),
                (__attribute__((address_space(3))) void*)(Ah + p*8), 16, 0, 0);
            __builtin_amdgcn_global_load_lds(
                (const __attribute__((address_space(1))) void*)(Bsrc + (size_t)row*HID + c*8),
                (__attribute__((address_space(3))) void*)(Bh + p*8), 16, 0, 0);
        }
        __syncthreads();

        #pragma unroll
        for (int kk = 0; kk < 2; ++kk) {
            f16x8 a[4], b[2];
            #pragma unroll
            for (int i = 0; i < 4; ++i) {
                const int ra = wm + i*16 + fr;
                a[i] = *(const f16x8*)(Ah + (ra*8 + ((kk*4 + quad) ^ (ra & 7)))*8);
            }
            #pragma unroll
            for (int j = 0; j < 2; ++j) {
                const int rb = wn + j*16 + fr;
                b[j] = *(const f16x8*)(Bh + (rb*8 + ((kk*4 + quad) ^ (rb & 7)))*8);
            }
            #pragma unroll
            for (int i = 0; i < 4; ++i)
                #pragma unroll
                for (int j = 0; j < 2; ++j)
                    acc[i][j] = __builtin_amdgcn_mfma_f32_16x16x32_f16(a[i], b[j], acc[i][j], 0, 0, 0);
        }
    }

    #pragma unroll
    for (int j = 0; j < 2; ++j) {
        const int o = on0 + wn + j*16 + fr;
        const float bb = bo[o];
        #pragma unroll
        for (int i = 0; i < 4; ++i)
            #pragma unroll
            for (int rg = 0; rg < 4; ++rg) {
                const int t = tm0 + wm + i*16 + quad*4 + rg;
                Y[(size_t)t*HID + o] = acc[i][j][rg] + bb;
            }
    }
}

// ---------------------------------------------------------------------------
// Launch.  Workspace (ushort units, 117 MB):
//   Qb,Kb f16 [B,H,S,D]; Vb f16 [B,H,D,S'] (sigma-permuted)
//   Of f16 [t][HID] token-major (attn output)
//   Xh f16; Wq/Wk/Wv/Wo f16
// ---------------------------------------------------------------------------
extern "C" void kernel_launch(void* const* d_in, const int* in_sizes, int n_in,
                              void* d_out, int out_size, void* d_ws, size_t ws_size,
                              hipStream_t stream)
{
    const float* X  = (const float*)d_in[0];
    const float* wq = (const float*)d_in[1];
    const float* bq = (const float*)d_in[2];
    const float* wk = (const float*)d_in[3];
    const float* bk = (const float*)d_in[4];
    const float* wv = (const float*)d_in[5];
    const float* bv = (const float*)d_in[6];
    const float* wo = (const float*)d_in[7];
    const float* bo = (const float*)d_in[8];
    float* Y = (float*)d_out;

    const size_t F  = (size_t)NT * HID;    // 8,388,608
    const size_t Wn = (size_t)HID * HID;   // 4,194,304

    unsigned short* Qb  = (unsigned short*)d_ws;
    unsigned short* Kb  = Qb  + F;
    unsigned short* Vb  = Kb  + F;     // [B,H,D,S'] permuted
    unsigned short* Of  = Vb  + F;     // token-major [t][HID]
    unsigned short* Xh  = Of  + F;
    unsigned short* Wqh = Xh  + F;
    unsigned short* Wkh = Wqh + Wn;
    unsigned short* Wvh = Wkh + Wn;
    unsigned short* Woh = Wvh + Wn;

    cast_x<<<(int)(F/4/256), 256, 0, stream>>>(X, Xh, (int)(F/4));
    cast_w4<<<dim3((int)(Wn/4/256), 4), 256, 0, stream>>>(
        wq, wk, wv, wo, Wqh, Wkh, Wvh, Woh, (int)(Wn/4));

    qkv_f16<<<dim3(HID/128, NT/128, 3), 256, 0, stream>>>(
        Xh, Wqh, Wkh, Wvh, bq, bk, bv, Qb, Kb, Vb);

    attn_mfma<<<dim3(512, 1, 1), 512, 0, stream>>>(Qb, Kb, Vb, Of);

    oproj_f16<<<dim3(HID/128, NT/128), 512, 0, stream>>>(Of, Woh, bo, Y);
}